// Round 5
// baseline (462.865 us; speedup 1.0000x reference)
//
#include <hip/hip_runtime.h>

#define DD 128
#define SCAN_CHUNK 2048   // 256 threads x 8 elements per scan block
#define PAD1 16           // cnt1 stride: one counter per 64B line
#define PAD2 8            // cnt2 stride: two counters per 64B line

typedef __attribute__((ext_vector_type(8))) short bf16x8;
typedef __attribute__((ext_vector_type(4))) float f32x4;

__device__ __forceinline__ short f2bf(float f) {
    union { float f; unsigned u; } x; x.f = f;
    unsigned r = x.u + 0x7FFF + ((x.u >> 16) & 1);   // round-to-nearest-even
    return (short)(r >> 16);
}

// ---------------------------------------------------------------------------
// k_hist2: histogram both graphs into PADDED counters (one/two per 64B line
// -> no per-line serialization at the coherence point) and capture each
// element's rank (atomicAdd return). 8 elements per thread -> 8 chains.
// ---------------------------------------------------------------------------
__global__ __launch_bounds__(256)
void k_hist2(const int* __restrict__ g1d, const int* __restrict__ g2d,
             int* __restrict__ cnt1p, int* __restrict__ cnt2p,
             int* __restrict__ rank1, int* __restrict__ rank2,
             int nnz, int no) {
    int gid = blockIdx.x * 256 + threadIdx.x;
    const int* dst; int* cnt; int* rank; int q; int str;
    if (gid < no) { dst = g1d; cnt = cnt1p; rank = rank1; str = PAD1; q = gid; }
    else {
        q = gid - no;
        if (q >= no) return;
        dst = g2d; cnt = cnt2p; rank = rank2; str = PAD2;
    }
    int i = q << 3;
    if (i + 8 <= nnz) {
        int4 d0 = *(const int4*)(dst + i);
        int4 d1 = *(const int4*)(dst + i + 4);
        int r0 = atomicAdd(&cnt[d0.x * str], 1);
        int r1 = atomicAdd(&cnt[d0.y * str], 1);
        int r2 = atomicAdd(&cnt[d0.z * str], 1);
        int r3 = atomicAdd(&cnt[d0.w * str], 1);
        int r4 = atomicAdd(&cnt[d1.x * str], 1);
        int r5 = atomicAdd(&cnt[d1.y * str], 1);
        int r6 = atomicAdd(&cnt[d1.z * str], 1);
        int r7 = atomicAdd(&cnt[d1.w * str], 1);
        *(int4*)(rank + i)     = make_int4(r0, r1, r2, r3);
        *(int4*)(rank + i + 4) = make_int4(r4, r5, r6, r7);
    } else {
        for (; i < nnz; ++i) rank[i] = atomicAdd(&cnt[dst[i] * str], 1);
    }
}

__global__ __launch_bounds__(256)
void k_scan_blocks2(const int* __restrict__ cnt1, int* __restrict__ off1,
                    const int* __restrict__ cnt2, int* __restrict__ off2,
                    int* __restrict__ bsum, int n1, int n2, int nb1) {
    __shared__ int sh[256];
    const int tid = threadIdx.x;
    const int b = blockIdx.x;
    const int* cnt; int* off; int* bs; int n; int lb; int str;
    if (b < nb1) { cnt = cnt1; off = off1; bs = bsum;      n = n1; lb = b;       str = PAD1; }
    else         { cnt = cnt2; off = off2; bs = bsum + 64; n = n2; lb = b - nb1; str = PAD2; }

    const int base = lb * SCAN_CHUNK + tid * 8;
    int v[8];
    int s = 0;
    #pragma unroll
    for (int j = 0; j < 8; ++j) {
        int idx = base + j;
        v[j] = (idx < n) ? cnt[(size_t)idx * str] : 0;
        s += v[j];
    }
    sh[tid] = s;
    __syncthreads();
    for (int d = 1; d < 256; d <<= 1) {
        int y = (tid >= d) ? sh[tid - d] : 0;
        __syncthreads();
        sh[tid] += y;
        __syncthreads();
    }
    int incl = sh[tid];
    int run = incl - s;
    #pragma unroll
    for (int j = 0; j < 8; ++j) {
        int idx = base + j;
        if (idx < n) off[idx] = run;
        run += v[j];
    }
    if (tid == 255) bs[lb] = incl;
}

__global__ void k_scan_top2(int* __restrict__ bsum, int nb1, int nb2) {
    if (threadIdx.x == 0) {
        int run = 0;
        for (int i = 0; i < nb1; ++i) { int t = bsum[i]; bsum[i] = run; run += t; }
    } else if (threadIdx.x == 1) {
        int run = 0;
        for (int i = 0; i < nb2; ++i) { int t = bsum[64 + i]; bsum[64 + i] = run; run += t; }
    }
}

__global__ __launch_bounds__(256)
void k_scan_add2(int* __restrict__ off1, int* __restrict__ off2,
                 const int* __restrict__ bsum, int n1, int n2, int nnz) {
    int gid = blockIdx.x * 256 + threadIdx.x;
    if (gid < n1) {
        off1[gid] += bsum[gid >> 11];            // SCAN_CHUNK == 2048
    } else {
        int g = gid - n1;
        if (g < n2) off2[g] += bsum[64 + (g >> 11)];
    }
    if (gid == 0) { off1[n1] = nnz; off2[n2] = nnz; }
}

// ---------------------------------------------------------------------------
// k_fill2: srcs[off[d] + rank[i]] = src[i]. No atomics; fire-and-forget.
// ---------------------------------------------------------------------------
__global__ __launch_bounds__(256)
void k_fill2(const int* __restrict__ g1d, const int* __restrict__ g1s,
             const int* __restrict__ off1, const int* __restrict__ rank1,
             int* __restrict__ srcs1,
             const int* __restrict__ g2d, const int* __restrict__ g2s,
             const int* __restrict__ off2, const int* __restrict__ rank2,
             int* __restrict__ srcs2,
             int nnz, int nq) {
    int gid = blockIdx.x * 256 + threadIdx.x;
    const int* dst; const int* src; const int* off; const int* rank; int* out; int q;
    if (gid < nq) { dst = g1d; src = g1s; off = off1; rank = rank1; out = srcs1; q = gid; }
    else {
        q = gid - nq;
        if (q >= nq) return;
        dst = g2d; src = g2s; off = off2; rank = rank2; out = srcs2;
    }
    int i = q << 2;
    if (i + 4 <= nnz) {
        int4 d = *(const int4*)(dst + i);
        int4 s = *(const int4*)(src + i);
        int4 r = *(const int4*)(rank + i);
        int o0 = off[d.x];
        int o1 = off[d.y];
        int o2 = off[d.z];
        int o3 = off[d.w];
        out[o0 + r.x] = s.x;
        out[o1 + r.y] = s.y;
        out[o2 + r.z] = s.z;
        out[o3 + r.w] = s.w;
    } else {
        for (; i < nnz; ++i) out[off[dst[i]] + rank[i]] = src[i];
    }
}

// ---------------------------------------------------------------------------
// k_edge_gather: Xe[e] = degE[e] * sum_{j in seg(e)} X[srcs1[j]]
// half-wave per edge row; float4 per lane; 8-way unrolled.
// ---------------------------------------------------------------------------
__global__ __launch_bounds__(256)
void k_edge_gather(const float* __restrict__ X, const int* __restrict__ off,
                   const int* __restrict__ srcs, const float* __restrict__ degE,
                   float* __restrict__ Xe, int n_edges) {
    int gid = blockIdx.x * 256 + threadIdx.x;
    int e = gid >> 5;
    if (e >= n_edges) return;
    int k = (gid & 31) << 2;
    int beg = off[e], end = off[e + 1];
    float4 acc0 = {0, 0, 0, 0}, acc1 = {0, 0, 0, 0};
    float4 acc2 = {0, 0, 0, 0}, acc3 = {0, 0, 0, 0};
    int j = beg;
    for (; j + 8 <= end; j += 8) {
        int s0 = srcs[j + 0];
        int s1 = srcs[j + 1];
        int s2 = srcs[j + 2];
        int s3 = srcs[j + 3];
        int s4 = srcs[j + 4];
        int s5 = srcs[j + 5];
        int s6 = srcs[j + 6];
        int s7 = srcs[j + 7];
        float4 v0 = *(const float4*)(X + (size_t)s0 * DD + k);
        float4 v1 = *(const float4*)(X + (size_t)s1 * DD + k);
        float4 v2 = *(const float4*)(X + (size_t)s2 * DD + k);
        float4 v3 = *(const float4*)(X + (size_t)s3 * DD + k);
        float4 v4 = *(const float4*)(X + (size_t)s4 * DD + k);
        float4 v5 = *(const float4*)(X + (size_t)s5 * DD + k);
        float4 v6 = *(const float4*)(X + (size_t)s6 * DD + k);
        float4 v7 = *(const float4*)(X + (size_t)s7 * DD + k);
        acc0.x += v0.x; acc0.y += v0.y; acc0.z += v0.z; acc0.w += v0.w;
        acc1.x += v1.x; acc1.y += v1.y; acc1.z += v1.z; acc1.w += v1.w;
        acc2.x += v2.x; acc2.y += v2.y; acc2.z += v2.z; acc2.w += v2.w;
        acc3.x += v3.x; acc3.y += v3.y; acc3.z += v3.z; acc3.w += v3.w;
        acc0.x += v4.x; acc0.y += v4.y; acc0.z += v4.z; acc0.w += v4.w;
        acc1.x += v5.x; acc1.y += v5.y; acc1.z += v5.z; acc1.w += v5.w;
        acc2.x += v6.x; acc2.y += v6.y; acc2.z += v6.z; acc2.w += v6.w;
        acc3.x += v7.x; acc3.y += v7.y; acc3.z += v7.z; acc3.w += v7.w;
    }
    for (; j < end; ++j) {
        int s = srcs[j];
        float4 v = *(const float4*)(X + (size_t)s * DD + k);
        acc0.x += v.x; acc0.y += v.y; acc0.z += v.z; acc0.w += v.w;
    }
    float f = degE[e];
    float4 o;
    o.x = f * ((acc0.x + acc1.x) + (acc2.x + acc3.x));
    o.y = f * ((acc0.y + acc1.y) + (acc2.y + acc3.y));
    o.z = f * ((acc0.z + acc1.z) + (acc2.z + acc3.z));
    o.w = f * ((acc0.w + acc1.w) + (acc2.w + acc3.w));
    *(float4*)(Xe + (size_t)e * DD + k) = o;
}

// ---------------------------------------------------------------------------
// k_node_gather: Xi[v] = (1-a)*degV[v] * sum Xe[srcs2[j]] + a*X0[v]  (-> d_out)
// ---------------------------------------------------------------------------
__global__ __launch_bounds__(256)
void k_node_gather(const float* __restrict__ Xe, const int* __restrict__ off,
                   const int* __restrict__ srcs, const float* __restrict__ degV,
                   const float* __restrict__ X0, const float* __restrict__ alphaP,
                   float* __restrict__ Xi, int n_nodes) {
    int gid = blockIdx.x * 256 + threadIdx.x;
    int v = gid >> 5;
    if (v >= n_nodes) return;
    int k = (gid & 31) << 2;
    int beg = off[v], end = off[v + 1];
    float4 acc0 = {0, 0, 0, 0}, acc1 = {0, 0, 0, 0};
    int j = beg;
    for (; j + 4 <= end; j += 4) {
        int s0 = srcs[j + 0];
        int s1 = srcs[j + 1];
        int s2 = srcs[j + 2];
        int s3 = srcs[j + 3];
        float4 v0 = *(const float4*)(Xe + (size_t)s0 * DD + k);
        float4 v1 = *(const float4*)(Xe + (size_t)s1 * DD + k);
        float4 v2 = *(const float4*)(Xe + (size_t)s2 * DD + k);
        float4 v3 = *(const float4*)(Xe + (size_t)s3 * DD + k);
        acc0.x += v0.x; acc0.y += v0.y; acc0.z += v0.z; acc0.w += v0.w;
        acc1.x += v1.x; acc1.y += v1.y; acc1.z += v1.z; acc1.w += v1.w;
        acc0.x += v2.x; acc0.y += v2.y; acc0.z += v2.z; acc0.w += v2.w;
        acc1.x += v3.x; acc1.y += v3.y; acc1.z += v3.z; acc1.w += v3.w;
    }
    for (; j < end; ++j) {
        int s = srcs[j];
        float4 x = *(const float4*)(Xe + (size_t)s * DD + k);
        acc0.x += x.x; acc0.y += x.y; acc0.z += x.z; acc0.w += x.w;
    }
    float a = alphaP[0];
    float f = (1.0f - a) * degV[v];
    float4 x0 = *(const float4*)(X0 + (size_t)v * DD + k);
    float4 o;
    o.x = f * (acc0.x + acc1.x) + a * x0.x;
    o.y = f * (acc0.y + acc1.y) + a * x0.y;
    o.z = f * (acc0.z + acc1.z) + a * x0.z;
    o.w = f * (acc0.w + acc1.w) + a * x0.w;
    *(float4*)(Xi + (size_t)v * DD + k) = o;
}

// ---------------------------------------------------------------------------
// k_gemm_mfma: out = (1-b)*Xi + b*(Xi @ W^T) in place, bf16 MFMA.
// One wave per 16-row strip. B-frags (all of W, bf16) converted once per wave
// into registers: layout B[n=lane&15][k=quad*8+j] == W rows (k-contiguous).
// A-frags per strip: A[m=lane&15][k=quad*8+j] from Xi rows. C/D layout:
// col=lane&15, row=quad*4+reg (m89-verified). Epilogue re-reads Xi (L1-hot,
// same strip just loaded) in fp32 for the (1-b)*Xi term. In-place safe:
// all A loads of the strip complete (waitcnt before first MFMA consumption)
// before any epilogue store; strips are wave-disjoint.
// ---------------------------------------------------------------------------
__global__ __launch_bounds__(256)
void k_gemm_mfma(float* xio, const float* __restrict__ W,
                 const float* __restrict__ betaP, int n_rows, int nstrips) {
    const int lane = threadIdx.x & 63;
    const int wid  = threadIdx.x >> 6;
    const int m16  = lane & 15;
    const int quad = lane >> 4;
    const int kq   = quad * 8;

    const float b  = betaP[0];
    const float ib = 1.0f - b;

    // Convert W into 32 B-fragments (8 ntiles x 4 kfrags), kept in VGPRs.
    bf16x8 bf[8][4];
    #pragma unroll
    for (int nt = 0; nt < 8; ++nt) {
        const float* wr = W + (size_t)(nt * 16 + m16) * DD;
        #pragma unroll
        for (int kf = 0; kf < 4; ++kf) {
            const float* p = wr + kf * 32 + kq;
            float4 lo = *(const float4*)p;
            float4 hi = *(const float4*)(p + 4);
            bf16x8 t;
            t[0] = f2bf(lo.x); t[1] = f2bf(lo.y); t[2] = f2bf(lo.z); t[3] = f2bf(lo.w);
            t[4] = f2bf(hi.x); t[5] = f2bf(hi.y); t[6] = f2bf(hi.z); t[7] = f2bf(hi.w);
            bf[nt][kf] = t;
        }
    }

    const int nwaves = gridDim.x * 4;
    for (int strip = blockIdx.x * 4 + wid; strip < nstrips; strip += nwaves) {
        const int row0 = strip * 16;
        int arow = row0 + m16;
        if (arow >= n_rows) arow = n_rows - 1;     // tail-safe (inert when M%16==0)
        const float* xr = xio + (size_t)arow * DD;
        bf16x8 af[4];
        #pragma unroll
        for (int kf = 0; kf < 4; ++kf) {
            const float* p = xr + kf * 32 + kq;
            float4 lo = *(const float4*)p;
            float4 hi = *(const float4*)(p + 4);
            bf16x8 t;
            t[0] = f2bf(lo.x); t[1] = f2bf(lo.y); t[2] = f2bf(lo.z); t[3] = f2bf(lo.w);
            t[4] = f2bf(hi.x); t[5] = f2bf(hi.y); t[6] = f2bf(hi.z); t[7] = f2bf(hi.w);
            af[kf] = t;
        }
        #pragma unroll
        for (int nt = 0; nt < 8; ++nt) {
            f32x4 acc = {0.f, 0.f, 0.f, 0.f};
            #pragma unroll
            for (int kf = 0; kf < 4; ++kf)
                acc = __builtin_amdgcn_mfma_f32_16x16x32_bf16(af[kf], bf[nt][kf], acc, 0, 0, 0);
            const int col = nt * 16 + m16;
            #pragma unroll
            for (int r = 0; r < 4; ++r) {
                int row = row0 + quad * 4 + r;
                if (row < n_rows) {
                    float* p = xio + (size_t)row * DD + col;
                    *p = ib * (*p) + b * acc[r];
                }
            }
        }
    }
}

// ---------------------------------------------------------------------------
extern "C" void kernel_launch(void* const* d_in, const int* in_sizes, int n_in,
                              void* d_out, int out_size, void* d_ws, size_t ws_size,
                              hipStream_t stream) {
    const float* X     = (const float*)d_in[0];
    const float* X0    = (const float*)d_in[1];
    const float* degE  = (const float*)d_in[2];
    const float* degV  = (const float*)d_in[3];
    const float* alpha = (const float*)d_in[4];
    const float* beta  = (const float*)d_in[5];
    const float* W     = (const float*)d_in[6];
    const int*   g1s   = (const int*)d_in[7];
    const int*   g1d   = (const int*)d_in[8];
    const int*   g2s   = (const int*)d_in[9];
    const int*   g2d   = (const int*)d_in[10];
    float* out = (float*)d_out;

    const int n_nodes = in_sizes[3];        // 100000
    const int n_edges = in_sizes[2];        // 20000
    const int nnz     = in_sizes[7];        // 800000

    // --- workspace layout (4-byte units) ---
    // rank1/rank2 overlay Xe (dead before edge_gather writes Xe).
    // Padded counters overlay srcs1/srcs2 (dead until k_fill2, after scan).
    int*   wsi   = (int*)d_ws;
    float* Xe    = (float*)d_ws;                       // [E*128] (10.24 MB)
    int*   rank1 = wsi;                                // [nnz]   (overlays Xe)
    int*   rank2 = wsi + nnz;                          // [nnz]   (overlays Xe)
    size_t o     = (size_t)n_edges * DD;
    int*   off1  = wsi + o;          o += n_edges + 1;
    int*   off2  = wsi + o;          o += n_nodes + 1;
    size_t srcs_base = o;
    int*   srcs1 = wsi + o;          o += nnz;
    int*   srcs2 = wsi + o;          o += nnz;
    int*   bsum  = wsi + o;          o += 128;
    int*   cnt1p = wsi + srcs_base;                    // [n_edges*PAD1] overlays srcs
    int*   cnt2p = cnt1p + (size_t)n_edges * PAD1;     // [n_nodes*PAD2]

    // zero padded counters (contiguous): 20000*16 + 100000*8 ints = 4.48 MB
    hipMemsetAsync(cnt1p, 0,
                   ((size_t)n_edges * PAD1 + (size_t)n_nodes * PAD2) * sizeof(int),
                   stream);

    const int nb1 = (n_edges + SCAN_CHUNK - 1) / SCAN_CHUNK;   // 10
    const int nb2 = (n_nodes + SCAN_CHUNK - 1) / SCAN_CHUNK;   // 49
    const int no  = (nnz + 7) / 8;                             // octs per graph
    const int oblb = (2 * no + 255) / 256;
    const int nq  = (nnz + 3) / 4;                             // quads per graph
    const int qblb = (2 * nq + 255) / 256;

    // ---- fused CSR build for g1 (dst=hyperedge) and g2 (dst=node) ----
    k_hist2<<<oblb, 256, 0, stream>>>(g1d, g2d, cnt1p, cnt2p, rank1, rank2, nnz, no);
    k_scan_blocks2<<<nb1 + nb2, 256, 0, stream>>>(cnt1p, off1, cnt2p, off2, bsum,
                                                  n_edges, n_nodes, nb1);
    k_scan_top2<<<1, 64, 0, stream>>>(bsum, nb1, nb2);
    k_scan_add2<<<(n_edges + n_nodes + 255) / 256, 256, 0, stream>>>(
        off1, off2, bsum, n_edges, n_nodes, nnz);
    k_fill2<<<qblb, 256, 0, stream>>>(g1d, g1s, off1, rank1, srcs1,
                                      g2d, g2s, off2, rank2, srcs2, nnz, nq);

    // ---- gather phases ----
    k_edge_gather<<<(n_edges * 32 + 255) / 256, 256, 0, stream>>>(
        X, off1, srcs1, degE, Xe, n_edges);
    k_node_gather<<<(n_nodes * 32 + 255) / 256, 256, 0, stream>>>(
        Xe, off2, srcs2, degV, X0, alpha, out, n_nodes);

    // ---- out = (1-b)*Xi + b*(Xi @ W^T), in place, bf16 MFMA ----
    const int nstrips = (n_nodes + 15) / 16;           // 6250
    k_gemm_mfma<<<(nstrips + 3) / 4, 256, 0, stream>>>(out, W, beta, n_nodes, nstrips);
}

// Round 6
// 405.429 us; speedup vs baseline: 1.1417x; 1.1417x over previous
//
#include <hip/hip_runtime.h>

#define DD 128
#define SCAN_CHUNK 2048   // 256 threads x 8 elements per scan block
#define PAD1 16           // cnt1 stride: one counter per 64B line
#define PAD2 8            // cnt2 stride: two counters per 64B line

typedef __attribute__((ext_vector_type(8))) short bf16x8;
typedef __attribute__((ext_vector_type(4))) float f32x4;

__device__ __forceinline__ short f2bf(float f) {
    union { float f; unsigned u; } x; x.f = f;
    unsigned r = x.u + 0x7FFF + ((x.u >> 16) & 1);   // round-to-nearest-even
    return (short)(r >> 16);
}

// ---------------------------------------------------------------------------
// k_hist2: histogram both graphs into PADDED counters (no per-line
// serialization at the coherence point) and capture each element's rank
// (atomicAdd return). 8 elements per thread -> 8 independent atomic chains.
// ---------------------------------------------------------------------------
__global__ __launch_bounds__(256)
void k_hist2(const int* __restrict__ g1d, const int* __restrict__ g2d,
             int* __restrict__ cnt1p, int* __restrict__ cnt2p,
             int* __restrict__ rank1, int* __restrict__ rank2,
             int nnz, int no) {
    int gid = blockIdx.x * 256 + threadIdx.x;
    const int* dst; int* cnt; int* rank; int q; int str;
    if (gid < no) { dst = g1d; cnt = cnt1p; rank = rank1; str = PAD1; q = gid; }
    else {
        q = gid - no;
        if (q >= no) return;
        dst = g2d; cnt = cnt2p; rank = rank2; str = PAD2;
    }
    int i = q << 3;
    if (i + 8 <= nnz) {
        int4 d0 = *(const int4*)(dst + i);
        int4 d1 = *(const int4*)(dst + i + 4);
        int r0 = atomicAdd(&cnt[d0.x * str], 1);
        int r1 = atomicAdd(&cnt[d0.y * str], 1);
        int r2 = atomicAdd(&cnt[d0.z * str], 1);
        int r3 = atomicAdd(&cnt[d0.w * str], 1);
        int r4 = atomicAdd(&cnt[d1.x * str], 1);
        int r5 = atomicAdd(&cnt[d1.y * str], 1);
        int r6 = atomicAdd(&cnt[d1.z * str], 1);
        int r7 = atomicAdd(&cnt[d1.w * str], 1);
        *(int4*)(rank + i)     = make_int4(r0, r1, r2, r3);
        *(int4*)(rank + i + 4) = make_int4(r4, r5, r6, r7);
    } else {
        for (; i < nnz; ++i) rank[i] = atomicAdd(&cnt[dst[i] * str], 1);
    }
}

__global__ __launch_bounds__(256)
void k_scan_blocks2(const int* __restrict__ cnt1, int* __restrict__ off1,
                    const int* __restrict__ cnt2, int* __restrict__ off2,
                    int* __restrict__ bsum, int n1, int n2, int nb1) {
    __shared__ int sh[256];
    const int tid = threadIdx.x;
    const int b = blockIdx.x;
    const int* cnt; int* off; int* bs; int n; int lb; int str;
    if (b < nb1) { cnt = cnt1; off = off1; bs = bsum;      n = n1; lb = b;       str = PAD1; }
    else         { cnt = cnt2; off = off2; bs = bsum + 64; n = n2; lb = b - nb1; str = PAD2; }

    const int base = lb * SCAN_CHUNK + tid * 8;
    int v[8];
    int s = 0;
    #pragma unroll
    for (int j = 0; j < 8; ++j) {
        int idx = base + j;
        v[j] = (idx < n) ? cnt[(size_t)idx * str] : 0;
        s += v[j];
    }
    sh[tid] = s;
    __syncthreads();
    for (int d = 1; d < 256; d <<= 1) {
        int y = (tid >= d) ? sh[tid - d] : 0;
        __syncthreads();
        sh[tid] += y;
        __syncthreads();
    }
    int incl = sh[tid];
    int run = incl - s;
    #pragma unroll
    for (int j = 0; j < 8; ++j) {
        int idx = base + j;
        if (idx < n) off[idx] = run;
        run += v[j];
    }
    if (tid == 255) bs[lb] = incl;
}

__global__ void k_scan_top2(int* __restrict__ bsum, int nb1, int nb2) {
    if (threadIdx.x == 0) {
        int run = 0;
        for (int i = 0; i < nb1; ++i) { int t = bsum[i]; bsum[i] = run; run += t; }
    } else if (threadIdx.x == 1) {
        int run = 0;
        for (int i = 0; i < nb2; ++i) { int t = bsum[64 + i]; bsum[64 + i] = run; run += t; }
    }
}

__global__ __launch_bounds__(256)
void k_scan_add2(int* __restrict__ off1, int* __restrict__ off2,
                 const int* __restrict__ bsum, int n1, int n2, int nnz) {
    int gid = blockIdx.x * 256 + threadIdx.x;
    if (gid < n1) {
        off1[gid] += bsum[gid >> 11];            // SCAN_CHUNK == 2048
    } else {
        int g = gid - n1;
        if (g < n2) off2[g] += bsum[64 + (g >> 11)];
    }
    if (gid == 0) { off1[n1] = nnz; off2[n2] = nnz; }
}

// ---------------------------------------------------------------------------
// k_fill2: srcs[off[d] + rank[i]] = src[i]. No atomics; fire-and-forget.
// ---------------------------------------------------------------------------
__global__ __launch_bounds__(256)
void k_fill2(const int* __restrict__ g1d, const int* __restrict__ g1s,
             const int* __restrict__ off1, const int* __restrict__ rank1,
             int* __restrict__ srcs1,
             const int* __restrict__ g2d, const int* __restrict__ g2s,
             const int* __restrict__ off2, const int* __restrict__ rank2,
             int* __restrict__ srcs2,
             int nnz, int nq) {
    int gid = blockIdx.x * 256 + threadIdx.x;
    const int* dst; const int* src; const int* off; const int* rank; int* out; int q;
    if (gid < nq) { dst = g1d; src = g1s; off = off1; rank = rank1; out = srcs1; q = gid; }
    else {
        q = gid - nq;
        if (q >= nq) return;
        dst = g2d; src = g2s; off = off2; rank = rank2; out = srcs2;
    }
    int i = q << 2;
    if (i + 4 <= nnz) {
        int4 d = *(const int4*)(dst + i);
        int4 s = *(const int4*)(src + i);
        int4 r = *(const int4*)(rank + i);
        int o0 = off[d.x];
        int o1 = off[d.y];
        int o2 = off[d.z];
        int o3 = off[d.w];
        out[o0 + r.x] = s.x;
        out[o1 + r.y] = s.y;
        out[o2 + r.z] = s.z;
        out[o3 + r.w] = s.w;
    } else {
        for (; i < nnz; ++i) out[off[dst[i]] + rank[i]] = src[i];
    }
}

// ---------------------------------------------------------------------------
// k_edge_gather: Xe[e] = degE[e] * sum_{j in seg(e)} X[srcs1[j]]
// half-wave per edge row; float4 per lane; 8-way unrolled.
// ---------------------------------------------------------------------------
__global__ __launch_bounds__(256)
void k_edge_gather(const float* __restrict__ X, const int* __restrict__ off,
                   const int* __restrict__ srcs, const float* __restrict__ degE,
                   float* __restrict__ Xe, int n_edges) {
    int gid = blockIdx.x * 256 + threadIdx.x;
    int e = gid >> 5;
    if (e >= n_edges) return;
    int k = (gid & 31) << 2;
    int beg = off[e], end = off[e + 1];
    float4 acc0 = {0, 0, 0, 0}, acc1 = {0, 0, 0, 0};
    float4 acc2 = {0, 0, 0, 0}, acc3 = {0, 0, 0, 0};
    int j = beg;
    for (; j + 8 <= end; j += 8) {
        int s0 = srcs[j + 0];
        int s1 = srcs[j + 1];
        int s2 = srcs[j + 2];
        int s3 = srcs[j + 3];
        int s4 = srcs[j + 4];
        int s5 = srcs[j + 5];
        int s6 = srcs[j + 6];
        int s7 = srcs[j + 7];
        float4 v0 = *(const float4*)(X + (size_t)s0 * DD + k);
        float4 v1 = *(const float4*)(X + (size_t)s1 * DD + k);
        float4 v2 = *(const float4*)(X + (size_t)s2 * DD + k);
        float4 v3 = *(const float4*)(X + (size_t)s3 * DD + k);
        float4 v4 = *(const float4*)(X + (size_t)s4 * DD + k);
        float4 v5 = *(const float4*)(X + (size_t)s5 * DD + k);
        float4 v6 = *(const float4*)(X + (size_t)s6 * DD + k);
        float4 v7 = *(const float4*)(X + (size_t)s7 * DD + k);
        acc0.x += v0.x; acc0.y += v0.y; acc0.z += v0.z; acc0.w += v0.w;
        acc1.x += v1.x; acc1.y += v1.y; acc1.z += v1.z; acc1.w += v1.w;
        acc2.x += v2.x; acc2.y += v2.y; acc2.z += v2.z; acc2.w += v2.w;
        acc3.x += v3.x; acc3.y += v3.y; acc3.z += v3.z; acc3.w += v3.w;
        acc0.x += v4.x; acc0.y += v4.y; acc0.z += v4.z; acc0.w += v4.w;
        acc1.x += v5.x; acc1.y += v5.y; acc1.z += v5.z; acc1.w += v5.w;
        acc2.x += v6.x; acc2.y += v6.y; acc2.z += v6.z; acc2.w += v6.w;
        acc3.x += v7.x; acc3.y += v7.y; acc3.z += v7.z; acc3.w += v7.w;
    }
    for (; j < end; ++j) {
        int s = srcs[j];
        float4 v = *(const float4*)(X + (size_t)s * DD + k);
        acc0.x += v.x; acc0.y += v.y; acc0.z += v.z; acc0.w += v.w;
    }
    float f = degE[e];
    float4 o;
    o.x = f * ((acc0.x + acc1.x) + (acc2.x + acc3.x));
    o.y = f * ((acc0.y + acc1.y) + (acc2.y + acc3.y));
    o.z = f * ((acc0.z + acc1.z) + (acc2.z + acc3.z));
    o.w = f * ((acc0.w + acc1.w) + (acc2.w + acc3.w));
    *(float4*)(Xe + (size_t)e * DD + k) = o;
}

// ---------------------------------------------------------------------------
// k_node_gather: Xi[v] = (1-a)*degV[v] * sum Xe[srcs2[j]] + a*X0[v]  (-> d_out)
// ---------------------------------------------------------------------------
__global__ __launch_bounds__(256)
void k_node_gather(const float* __restrict__ Xe, const int* __restrict__ off,
                   const int* __restrict__ srcs, const float* __restrict__ degV,
                   const float* __restrict__ X0, const float* __restrict__ alphaP,
                   float* __restrict__ Xi, int n_nodes) {
    int gid = blockIdx.x * 256 + threadIdx.x;
    int v = gid >> 5;
    if (v >= n_nodes) return;
    int k = (gid & 31) << 2;
    int beg = off[v], end = off[v + 1];
    float4 acc0 = {0, 0, 0, 0}, acc1 = {0, 0, 0, 0};
    int j = beg;
    for (; j + 4 <= end; j += 4) {
        int s0 = srcs[j + 0];
        int s1 = srcs[j + 1];
        int s2 = srcs[j + 2];
        int s3 = srcs[j + 3];
        float4 v0 = *(const float4*)(Xe + (size_t)s0 * DD + k);
        float4 v1 = *(const float4*)(Xe + (size_t)s1 * DD + k);
        float4 v2 = *(const float4*)(Xe + (size_t)s2 * DD + k);
        float4 v3 = *(const float4*)(Xe + (size_t)s3 * DD + k);
        acc0.x += v0.x; acc0.y += v0.y; acc0.z += v0.z; acc0.w += v0.w;
        acc1.x += v1.x; acc1.y += v1.y; acc1.z += v1.z; acc1.w += v1.w;
        acc0.x += v2.x; acc0.y += v2.y; acc0.z += v2.z; acc0.w += v2.w;
        acc1.x += v3.x; acc1.y += v3.y; acc1.z += v3.z; acc1.w += v3.w;
    }
    for (; j < end; ++j) {
        int s = srcs[j];
        float4 x = *(const float4*)(Xe + (size_t)s * DD + k);
        acc0.x += x.x; acc0.y += x.y; acc0.z += x.z; acc0.w += x.w;
    }
    float a = alphaP[0];
    float f = (1.0f - a) * degV[v];
    float4 x0 = *(const float4*)(X0 + (size_t)v * DD + k);
    float4 o;
    o.x = f * (acc0.x + acc1.x) + a * x0.x;
    o.y = f * (acc0.y + acc1.y) + a * x0.y;
    o.z = f * (acc0.z + acc1.z) + a * x0.z;
    o.w = f * (acc0.w + acc1.w) + a * x0.w;
    *(float4*)(Xi + (size_t)v * DD + k) = o;
}

// ---------------------------------------------------------------------------
// k_prep_w: M'[c][k] = bf16( b*W[c][k] + (1-b)*(c==k) ), row-major [128][128].
// Folds the GCNII identity blend into the weight matrix:
//   out = (1-b)*Xi + b*Xi@W^T  ==  Xi @ M'^T
// ---------------------------------------------------------------------------
__global__ __launch_bounds__(256)
void k_prep_w(const float* __restrict__ W, const float* __restrict__ betaP,
              short* __restrict__ Mbf) {
    int gid = blockIdx.x * 256 + threadIdx.x;   // 2048 threads, 8 elems each
    if (gid >= DD * DD / 8) return;
    int c  = gid >> 4;
    int k0 = (gid & 15) << 3;
    float b = betaP[0], ib = 1.0f - b;
    const float* p = W + c * DD + k0;
    float4 lo = *(const float4*)p, hi = *(const float4*)(p + 4);
    float v[8] = {lo.x, lo.y, lo.z, lo.w, hi.x, hi.y, hi.z, hi.w};
    bf16x8 t;
    #pragma unroll
    for (int j = 0; j < 8; ++j) {
        float m = b * v[j] + ((k0 + j) == c ? ib : 0.0f);
        t[j] = f2bf(m);
    }
    *(bf16x8*)(Mbf + (size_t)c * DD + k0) = t;
}

// ---------------------------------------------------------------------------
// k_gemm_mfma: out = Xi @ M'^T in place (xio = Xi = out), bf16 MFMA.
// One wave per 16-row strip, zero per-wave setup: B-frags are direct ushort8
// loads from M' (32 KB, L1-resident), A-frags converted from the strip's fp32
// rows. C/D layout col=lane&15, row=quad*4+reg (m89-verified). Pure stores
// (identity folded into M') — no RMW epilogue. In-place safe: the wave's A
// loads complete (vmcnt before MFMA) before any of its stores issue; strips
// are wave-disjoint.
// ---------------------------------------------------------------------------
__global__ __launch_bounds__(256)
void k_gemm_mfma(float* xio, const short* __restrict__ Mbf, int n_rows) {
    const int lane = threadIdx.x & 63;
    const int wid  = threadIdx.x >> 6;
    const int m16  = lane & 15;
    const int quad = lane >> 4;
    const int kq   = quad * 8;

    const int strip = blockIdx.x * 4 + wid;
    const int row0 = strip * 16;
    if (row0 >= n_rows) return;

    int arow = row0 + m16;
    if (arow >= n_rows) arow = n_rows - 1;       // inert when M%16==0
    const float* xr = xio + (size_t)arow * DD;

    bf16x8 af[4];
    #pragma unroll
    for (int kf = 0; kf < 4; ++kf) {
        const float* p = xr + kf * 32 + kq;
        float4 lo = *(const float4*)p;
        float4 hi = *(const float4*)(p + 4);
        bf16x8 t;
        t[0] = f2bf(lo.x); t[1] = f2bf(lo.y); t[2] = f2bf(lo.z); t[3] = f2bf(lo.w);
        t[4] = f2bf(hi.x); t[5] = f2bf(hi.y); t[6] = f2bf(hi.z); t[7] = f2bf(hi.w);
        af[kf] = t;
    }

    #pragma unroll
    for (int nt = 0; nt < 8; ++nt) {
        const short* mr = Mbf + (size_t)(nt * 16 + m16) * DD + kq;
        f32x4 acc = {0.f, 0.f, 0.f, 0.f};
        #pragma unroll
        for (int kf = 0; kf < 4; ++kf) {
            bf16x8 bfrag = *(const bf16x8*)(mr + kf * 32);
            acc = __builtin_amdgcn_mfma_f32_16x16x32_bf16(af[kf], bfrag, acc, 0, 0, 0);
        }
        const int col = nt * 16 + m16;
        #pragma unroll
        for (int r = 0; r < 4; ++r) {
            int row = row0 + quad * 4 + r;
            if (row < n_rows)
                xio[(size_t)row * DD + col] = acc[r];
        }
    }
}

// ---------------------------------------------------------------------------
extern "C" void kernel_launch(void* const* d_in, const int* in_sizes, int n_in,
                              void* d_out, int out_size, void* d_ws, size_t ws_size,
                              hipStream_t stream) {
    const float* X     = (const float*)d_in[0];
    const float* X0    = (const float*)d_in[1];
    const float* degE  = (const float*)d_in[2];
    const float* degV  = (const float*)d_in[3];
    const float* alpha = (const float*)d_in[4];
    const float* beta  = (const float*)d_in[5];
    const float* W     = (const float*)d_in[6];
    const int*   g1s   = (const int*)d_in[7];
    const int*   g1d   = (const int*)d_in[8];
    const int*   g2s   = (const int*)d_in[9];
    const int*   g2d   = (const int*)d_in[10];
    float* out = (float*)d_out;

    const int n_nodes = in_sizes[3];        // 100000
    const int n_edges = in_sizes[2];        // 20000
    const int nnz     = in_sizes[7];        // 800000

    // --- workspace layout (4-byte units) ---
    // rank1/rank2 overlay Xe (dead before edge_gather writes Xe).
    // Padded counters overlay srcs1/srcs2 (dead until k_fill2, after scan).
    int*   wsi   = (int*)d_ws;
    float* Xe    = (float*)d_ws;                       // [E*128] (10.24 MB)
    int*   rank1 = wsi;                                // [nnz]   (overlays Xe)
    int*   rank2 = wsi + nnz;                          // [nnz]   (overlays Xe)
    size_t o     = (size_t)n_edges * DD;
    int*   off1  = wsi + o;          o += n_edges + 1;
    int*   off2  = wsi + o;          o += n_nodes + 1;
    size_t srcs_base = o;
    int*   srcs1 = wsi + o;          o += nnz;
    int*   srcs2 = wsi + o;          o += nnz;
    int*   bsum  = wsi + o;          o += 128;
    short* Mbf   = (short*)(wsi + o); o += DD * DD / 2;  // bf16 [128][128]
    int*   cnt1p = wsi + srcs_base;                    // [n_edges*PAD1] overlays srcs
    int*   cnt2p = cnt1p + (size_t)n_edges * PAD1;     // [n_nodes*PAD2]

    // zero padded counters (contiguous): 20000*16 + 100000*8 ints = 4.48 MB
    hipMemsetAsync(cnt1p, 0,
                   ((size_t)n_edges * PAD1 + (size_t)n_nodes * PAD2) * sizeof(int),
                   stream);

    const int nb1 = (n_edges + SCAN_CHUNK - 1) / SCAN_CHUNK;   // 10
    const int nb2 = (n_nodes + SCAN_CHUNK - 1) / SCAN_CHUNK;   // 49
    const int no  = (nnz + 7) / 8;                             // octs per graph
    const int oblb = (2 * no + 255) / 256;
    const int nq  = (nnz + 3) / 4;                             // quads per graph
    const int qblb = (2 * nq + 255) / 256;

    // ---- fold (1-b)I + bW^T into bf16 M' (reused by the final GEMM) ----
    k_prep_w<<<(DD * DD / 8 + 255) / 256, 256, 0, stream>>>(W, beta, Mbf);

    // ---- fused CSR build for g1 (dst=hyperedge) and g2 (dst=node) ----
    k_hist2<<<oblb, 256, 0, stream>>>(g1d, g2d, cnt1p, cnt2p, rank1, rank2, nnz, no);
    k_scan_blocks2<<<nb1 + nb2, 256, 0, stream>>>(cnt1p, off1, cnt2p, off2, bsum,
                                                  n_edges, n_nodes, nb1);
    k_scan_top2<<<1, 64, 0, stream>>>(bsum, nb1, nb2);
    k_scan_add2<<<(n_edges + n_nodes + 255) / 256, 256, 0, stream>>>(
        off1, off2, bsum, n_edges, n_nodes, nnz);
    k_fill2<<<qblb, 256, 0, stream>>>(g1d, g1s, off1, rank1, srcs1,
                                      g2d, g2s, off2, rank2, srcs2, nnz, nq);

    // ---- gather phases ----
    k_edge_gather<<<(n_edges * 32 + 255) / 256, 256, 0, stream>>>(
        X, off1, srcs1, degE, Xe, n_edges);
    k_node_gather<<<(n_nodes * 32 + 255) / 256, 256, 0, stream>>>(
        Xe, off2, srcs2, degV, X0, alpha, out, n_nodes);

    // ---- out = Xi @ M'^T, in place, bf16 MFMA ----
    const int nstrips = (n_nodes + 15) / 16;           // 6250
    k_gemm_mfma<<<(nstrips + 3) / 4, 256, 0, stream>>>(out, Mbf, n_nodes);
}